// Round 2
// baseline (465.897 us; speedup 1.0000x reference)
//
#include <hip/hip_runtime.h>

#define N 8192
#define DIM 128
#define PACK 32        // floats per packed row record: [z0..z15, sq, inv, pad..]
#define P1_JCHUNK 16   // j-chunks in pass1 -> partial[P1_JCHUNK][N]

// ---------------------------------------------------------------------------
// Pass 0: encoder MLP. 128 -> 64 -> 32 -> 16 -> 16, relu on first three.
// One thread per row, 64-thread blocks (1 wave), weights staged in LDS.
// Writes packed[i] = {z[16], sq} (inv filled later by reduce_kernel).
// ---------------------------------------------------------------------------
__global__ __launch_bounds__(64) void encoder_kernel(
    const float* __restrict__ x,
    const float* __restrict__ W1, const float* __restrict__ b1,
    const float* __restrict__ W2, const float* __restrict__ b2,
    const float* __restrict__ W3, const float* __restrict__ b3,
    const float* __restrict__ W4, const float* __restrict__ b4,
    float* __restrict__ packed)
{
    __shared__ float sW2[64 * 32];
    __shared__ float sW3[32 * 16];
    __shared__ float sW4[16 * 16];
    __shared__ float sb1[64];
    __shared__ float sb2[32];
    __shared__ float sb3[16];
    __shared__ float sb4[16];
    __shared__ float sW1[128 * 64];   // reused for h2/h3 staging after layer 1
    __shared__ float sh1[64 * 65];    // stride 65: conflict-free

    int t = threadIdx.x;
    float* sh2 = sW1;                 // 64*33 = 2112 floats
    float* sh3 = sW1 + 2112;          // 64*17 = 1088 floats

    for (int idx = t; idx < 128 * 64; idx += 64) sW1[idx] = W1[idx];
    for (int idx = t; idx < 64 * 32; idx += 64) sW2[idx] = W2[idx];
    for (int idx = t; idx < 32 * 16; idx += 64) sW3[idx] = W3[idx];
    for (int idx = t; idx < 16 * 16; idx += 64) sW4[idx] = W4[idx];
    sb1[t] = b1[t];
    if (t < 32) sb2[t] = b2[t];
    if (t < 16) { sb3[t] = b3[t]; sb4[t] = b4[t]; }
    __syncthreads();

    int row = blockIdx.x * 64 + t;
    const float4* xr = (const float4*)(x + (size_t)row * DIM);

    // ---- layer 1: 128 -> 64 ----
    float h1[64];
    #pragma unroll
    for (int k = 0; k < 64; ++k) h1[k] = sb1[k];
    for (int j4 = 0; j4 < 32; ++j4) {
        float4 xv = xr[j4];
        const float* w0 = &sW1[(j4 * 4 + 0) * 64];
        const float* w1 = &sW1[(j4 * 4 + 1) * 64];
        const float* w2 = &sW1[(j4 * 4 + 2) * 64];
        const float* w3 = &sW1[(j4 * 4 + 3) * 64];
        #pragma unroll
        for (int k = 0; k < 64; ++k) h1[k] = fmaf(xv.x, w0[k], h1[k]);
        #pragma unroll
        for (int k = 0; k < 64; ++k) h1[k] = fmaf(xv.y, w1[k], h1[k]);
        #pragma unroll
        for (int k = 0; k < 64; ++k) h1[k] = fmaf(xv.z, w2[k], h1[k]);
        #pragma unroll
        for (int k = 0; k < 64; ++k) h1[k] = fmaf(xv.w, w3[k], h1[k]);
    }
    #pragma unroll
    for (int k = 0; k < 64; ++k) sh1[t * 65 + k] = fmaxf(h1[k], 0.0f);

    // ---- layer 2: 64 -> 32 ---- (single-wave block: in-order LDS ops)
    float h2[32];
    #pragma unroll
    for (int k = 0; k < 32; ++k) h2[k] = sb2[k];
    for (int j = 0; j < 64; ++j) {
        float a = sh1[t * 65 + j];
        #pragma unroll
        for (int k = 0; k < 32; ++k) h2[k] = fmaf(a, sW2[j * 32 + k], h2[k]);
    }
    #pragma unroll
    for (int k = 0; k < 32; ++k) sh2[t * 33 + k] = fmaxf(h2[k], 0.0f);

    // ---- layer 3: 32 -> 16 ----
    float h3[16];
    #pragma unroll
    for (int k = 0; k < 16; ++k) h3[k] = sb3[k];
    for (int j = 0; j < 32; ++j) {
        float a = sh2[t * 33 + j];
        #pragma unroll
        for (int k = 0; k < 16; ++k) h3[k] = fmaf(a, sW3[j * 16 + k], h3[k]);
    }
    #pragma unroll
    for (int k = 0; k < 16; ++k) sh3[t * 17 + k] = fmaxf(h3[k], 0.0f);

    // ---- layer 4: 16 -> 16, no relu ----
    float zo[16];
    #pragma unroll
    for (int k = 0; k < 16; ++k) zo[k] = sb4[k];
    for (int j = 0; j < 16; ++j) {
        float a = sh3[t * 17 + j];
        #pragma unroll
        for (int k = 0; k < 16; ++k) zo[k] = fmaf(a, sW4[j * 16 + k], zo[k]);
    }

    float s = 0.0f;
    #pragma unroll
    for (int k = 0; k < 16; ++k) s = fmaf(zo[k], zo[k], s);

    float* pr = packed + (size_t)row * PACK;
    float4* pv = (float4*)pr;
    pv[0] = make_float4(zo[0], zo[1], zo[2], zo[3]);
    pv[1] = make_float4(zo[4], zo[5], zo[6], zo[7]);
    pv[2] = make_float4(zo[8], zo[9], zo[10], zo[11]);
    pv[3] = make_float4(zo[12], zo[13], zo[14], zo[15]);
    pr[16] = s;
}

// ---------------------------------------------------------------------------
// Pass 1: row sums of numerator = 1/(1+dist). Thread owns row i (zi in
// VGPRs); the j loop is block-uniform so packed[j] reads scalarize to
// s_load_dwordx16 and feed v_fma(v,s,v) — no LDS, no divergent VMEM.
// Grid (32 i-blocks, P1_JCHUNK j-chunks).
// ---------------------------------------------------------------------------
__global__ __launch_bounds__(256) void pass1_kernel(
    const float* __restrict__ packed, float* __restrict__ partial)
{
    int t = threadIdx.x;
    int i = blockIdx.x * 256 + t;
    const int JPB = N / P1_JCHUNK;   // 512
    int jb = blockIdx.y * JPB;

    float zi[16];
    float sqi;
    {
        const float4* p = (const float4*)(packed + (size_t)i * PACK);
        #pragma unroll
        for (int q = 0; q < 4; ++q) {
            float4 v = p[q];
            zi[4*q] = v.x; zi[4*q+1] = v.y; zi[4*q+2] = v.z; zi[4*q+3] = v.w;
        }
        sqi = packed[(size_t)i * PACK + 16];
    }

    float acc = 0.0f;
    const float* pr = packed + (size_t)jb * PACK;
    #pragma unroll 2
    for (int j = 0; j < JPB; ++j, pr += PACK) {
        float d = 0.0f;
        #pragma unroll
        for (int k = 0; k < 16; ++k) d = fmaf(pr[k], zi[k], d);
        float dist = fmaxf(fmaf(-2.0f, d, sqi + pr[16]), 0.0f);
        acc += __builtin_amdgcn_rcpf(1.0f + dist);
    }
    partial[(size_t)blockIdx.y * N + i] = acc;
}

// ---------------------------------------------------------------------------
// Pass 1b: reduce partials, write inv into the packed record.
// ---------------------------------------------------------------------------
__global__ __launch_bounds__(256) void reduce_kernel(
    const float* __restrict__ partial, float* __restrict__ packed)
{
    int i = blockIdx.x * 256 + threadIdx.x;
    float s = 0.0f;
    #pragma unroll
    for (int c = 0; c < P1_JCHUNK; ++c) s += partial[(size_t)c * N + i];
    packed[(size_t)i * PACK + 17] = 1.0f / s;
}

// ---------------------------------------------------------------------------
// Pass 2: thread owns column j (zj in VGPRs); i loop is uniform -> zi, sqi,
// inv come from SGPRs (s_load). Coalesced nontemporal column-major stores
// (wave writes 256 B contiguous per i). Grid (32 j-blocks, 16 i-chunks).
// ---------------------------------------------------------------------------
__global__ __launch_bounds__(256) void pass2_kernel(
    const float* __restrict__ packed, float* __restrict__ out)
{
    int t = threadIdx.x;
    int j = blockIdx.x * 256 + t;
    const int IPB = N / 16;          // 512
    int i0 = blockIdx.y * IPB;

    float zj[16];
    float sqj;
    {
        const float4* p = (const float4*)(packed + (size_t)j * PACK);
        #pragma unroll
        for (int q = 0; q < 4; ++q) {
            float4 v = p[q];
            zj[4*q] = v.x; zj[4*q+1] = v.y; zj[4*q+2] = v.z; zj[4*q+3] = v.w;
        }
        sqj = packed[(size_t)j * PACK + 16];
    }

    const float* pr = packed + (size_t)i0 * PACK;
    float* op = out + (size_t)i0 * N + j;
    #pragma unroll 2
    for (int i = 0; i < IPB; ++i, pr += PACK, op += N) {
        float d = 0.0f;
        #pragma unroll
        for (int k = 0; k < 16; ++k) d = fmaf(pr[k], zj[k], d);
        float dist = fmaxf(fmaf(-2.0f, d, sqj + pr[16]), 0.0f);
        float num = __builtin_amdgcn_rcpf(1.0f + dist);
        __builtin_nontemporal_store(num * pr[17], op);
    }
}

extern "C" void kernel_launch(void* const* d_in, const int* in_sizes, int n_in,
                              void* d_out, int out_size, void* d_ws, size_t ws_size,
                              hipStream_t stream) {
    const float* x  = (const float*)d_in[0];
    const float* W1 = (const float*)d_in[1];
    const float* b1 = (const float*)d_in[2];
    const float* W2 = (const float*)d_in[3];
    const float* b2 = (const float*)d_in[4];
    const float* W3 = (const float*)d_in[5];
    const float* b3 = (const float*)d_in[6];
    const float* W4 = (const float*)d_in[7];
    const float* b4 = (const float*)d_in[8];
    float* out = (float*)d_out;

    float* ws = (float*)d_ws;
    float* packed  = ws;                         // N*PACK      = 262144 floats (1 MiB)
    float* partial = ws + (size_t)N * PACK;      // P1_JCHUNK*N = 131072 floats (512 KiB)

    encoder_kernel<<<128, 64, 0, stream>>>(x, W1, b1, W2, b2, W3, b3, W4, b4, packed);
    pass1_kernel<<<dim3(32, P1_JCHUNK), 256, 0, stream>>>(packed, partial);
    reduce_kernel<<<32, 256, 0, stream>>>(partial, packed);
    pass2_kernel<<<dim3(32, 16), 256, 0, stream>>>(packed, out);
}

// Round 3
// 398.531 us; speedup vs baseline: 1.1690x; 1.1690x over previous
//
#include <hip/hip_runtime.h>

#define N 8192
#define DIM 128
#define PACK 20    // floats per packed row record: [z0..z15, sq, pad, pad, pad] (80 B)
#define ROWS 4     // i-rows owned by each prob block (z held in VGPRs)

// ---------------------------------------------------------------------------
// Pass 0: encoder MLP. 128 -> 64 -> 32 -> 16 -> 16, relu on first three.
// One thread per row, 64-thread blocks (1 wave), weights staged in LDS.
// Writes packed[i] = {z[16], sq}.
// ---------------------------------------------------------------------------
__global__ __launch_bounds__(64) void encoder_kernel(
    const float* __restrict__ x,
    const float* __restrict__ W1, const float* __restrict__ b1,
    const float* __restrict__ W2, const float* __restrict__ b2,
    const float* __restrict__ W3, const float* __restrict__ b3,
    const float* __restrict__ W4, const float* __restrict__ b4,
    float* __restrict__ packed)
{
    __shared__ float sW2[64 * 32];
    __shared__ float sW3[32 * 16];
    __shared__ float sW4[16 * 16];
    __shared__ float sb1[64];
    __shared__ float sb2[32];
    __shared__ float sb3[16];
    __shared__ float sb4[16];
    __shared__ float sW1[128 * 64];   // reused for h2/h3 staging after layer 1
    __shared__ float sh1[64 * 65];    // stride 65: conflict-free

    int t = threadIdx.x;
    float* sh2 = sW1;                 // 64*33 = 2112 floats
    float* sh3 = sW1 + 2112;          // 64*17 = 1088 floats

    for (int idx = t; idx < 128 * 64; idx += 64) sW1[idx] = W1[idx];
    for (int idx = t; idx < 64 * 32; idx += 64) sW2[idx] = W2[idx];
    for (int idx = t; idx < 32 * 16; idx += 64) sW3[idx] = W3[idx];
    for (int idx = t; idx < 16 * 16; idx += 64) sW4[idx] = W4[idx];
    sb1[t] = b1[t];
    if (t < 32) sb2[t] = b2[t];
    if (t < 16) { sb3[t] = b3[t]; sb4[t] = b4[t]; }
    __syncthreads();

    int row = blockIdx.x * 64 + t;
    const float4* xr = (const float4*)(x + (size_t)row * DIM);

    // ---- layer 1: 128 -> 64 ----
    float h1[64];
    #pragma unroll
    for (int k = 0; k < 64; ++k) h1[k] = sb1[k];
    for (int j4 = 0; j4 < 32; ++j4) {
        float4 xv = xr[j4];
        const float* w0 = &sW1[(j4 * 4 + 0) * 64];
        const float* w1 = &sW1[(j4 * 4 + 1) * 64];
        const float* w2 = &sW1[(j4 * 4 + 2) * 64];
        const float* w3 = &sW1[(j4 * 4 + 3) * 64];
        #pragma unroll
        for (int k = 0; k < 64; ++k) h1[k] = fmaf(xv.x, w0[k], h1[k]);
        #pragma unroll
        for (int k = 0; k < 64; ++k) h1[k] = fmaf(xv.y, w1[k], h1[k]);
        #pragma unroll
        for (int k = 0; k < 64; ++k) h1[k] = fmaf(xv.z, w2[k], h1[k]);
        #pragma unroll
        for (int k = 0; k < 64; ++k) h1[k] = fmaf(xv.w, w3[k], h1[k]);
    }
    #pragma unroll
    for (int k = 0; k < 64; ++k) sh1[t * 65 + k] = fmaxf(h1[k], 0.0f);

    // ---- layer 2: 64 -> 32 ---- (single-wave block: in-order LDS ops)
    float h2[32];
    #pragma unroll
    for (int k = 0; k < 32; ++k) h2[k] = sb2[k];
    for (int j = 0; j < 64; ++j) {
        float a = sh1[t * 65 + j];
        #pragma unroll
        for (int k = 0; k < 32; ++k) h2[k] = fmaf(a, sW2[j * 32 + k], h2[k]);
    }
    #pragma unroll
    for (int k = 0; k < 32; ++k) sh2[t * 33 + k] = fmaxf(h2[k], 0.0f);

    // ---- layer 3: 32 -> 16 ----
    float h3[16];
    #pragma unroll
    for (int k = 0; k < 16; ++k) h3[k] = sb3[k];
    for (int j = 0; j < 32; ++j) {
        float a = sh2[t * 33 + j];
        #pragma unroll
        for (int k = 0; k < 16; ++k) h3[k] = fmaf(a, sW3[j * 16 + k], h3[k]);
    }
    #pragma unroll
    for (int k = 0; k < 16; ++k) sh3[t * 17 + k] = fmaxf(h3[k], 0.0f);

    // ---- layer 4: 16 -> 16, no relu ----
    float zo[16];
    #pragma unroll
    for (int k = 0; k < 16; ++k) zo[k] = sb4[k];
    for (int j = 0; j < 16; ++j) {
        float a = sh3[t * 17 + j];
        #pragma unroll
        for (int k = 0; k < 16; ++k) zo[k] = fmaf(a, sW4[j * 16 + k], zo[k]);
    }

    float s = 0.0f;
    #pragma unroll
    for (int k = 0; k < 16; ++k) s = fmaf(zo[k], zo[k], s);

    float* pr = packed + (size_t)row * PACK;
    float4* pv = (float4*)pr;
    pv[0] = make_float4(zo[0], zo[1], zo[2], zo[3]);
    pv[1] = make_float4(zo[4], zo[5], zo[6], zo[7]);
    pv[2] = make_float4(zo[8], zo[9], zo[10], zo[11]);
    pv[3] = make_float4(zo[12], zo[13], zo[14], zo[15]);
    pv[4] = make_float4(s, 0.0f, 0.0f, 0.0f);
}

// ---------------------------------------------------------------------------
// Fused probability kernel. Block b owns rows [4b, 4b+4); their z-vectors
// live in VGPRs for the whole kernel (loaded once). Thread t streams columns
// j = t + 256k with one coalesced 80B record load per step, producing 4
// outputs (64 FMA) per load. Phase A: full row sums (block covers all of j,
// so normalization needs no cross-block communication). Phase B: recompute
// numerators, scale, stream 4 coalesced nontemporal stores per step.
// ---------------------------------------------------------------------------
__global__ __launch_bounds__(256) void prob_kernel(
    const float* __restrict__ packed, float* __restrict__ out)
{
    int t = threadIdx.x;
    int i0 = blockIdx.x * ROWS;

    // i-side: 4 records -> registers, kept for the whole kernel
    float zi[ROWS][16];
    float sqi[ROWS];
    #pragma unroll
    for (int r = 0; r < ROWS; ++r) {
        const float4* p = (const float4*)(packed + (size_t)(i0 + r) * PACK);
        #pragma unroll
        for (int q = 0; q < 4; ++q) {
            float4 v = p[q];
            zi[r][4*q] = v.x; zi[r][4*q+1] = v.y; zi[r][4*q+2] = v.z; zi[r][4*q+3] = v.w;
        }
        sqi[r] = p[4].x;
    }

    // ---- phase A: row sums ----
    float acc[ROWS];
    #pragma unroll
    for (int r = 0; r < ROWS; ++r) acc[r] = 0.0f;

    #pragma unroll 2
    for (int js = 0; js < N / 256; ++js) {
        int j = js * 256 + t;
        const float4* p = (const float4*)(packed + (size_t)j * PACK);
        float4 v0 = p[0], v1 = p[1], v2 = p[2], v3 = p[3], v4 = p[4];
        float zj[16] = {v0.x, v0.y, v0.z, v0.w, v1.x, v1.y, v1.z, v1.w,
                        v2.x, v2.y, v2.z, v2.w, v3.x, v3.y, v3.z, v3.w};
        float sqj = v4.x;
        #pragma unroll
        for (int r = 0; r < ROWS; ++r) {
            float d0 = 0.0f, d1 = 0.0f;
            #pragma unroll
            for (int k = 0; k < 8; ++k) {
                d0 = fmaf(zi[r][2*k],   zj[2*k],   d0);
                d1 = fmaf(zi[r][2*k+1], zj[2*k+1], d1);
            }
            float dist = fmaxf(fmaf(-2.0f, d0 + d1, sqi[r] + sqj), 0.0f);
            acc[r] += __builtin_amdgcn_rcpf(1.0f + dist);
        }
    }

    // block-wide reduction of acc[r] (deterministic: butterfly + fixed-order LDS)
    __shared__ float red[4 * ROWS];
    int wave = t >> 6, lane = t & 63;
    #pragma unroll
    for (int r = 0; r < ROWS; ++r) {
        float v = acc[r];
        #pragma unroll
        for (int m = 1; m < 64; m <<= 1) v += __shfl_xor(v, m, 64);
        if (lane == 0) red[wave * ROWS + r] = v;
    }
    __syncthreads();
    float inv[ROWS];
    #pragma unroll
    for (int r = 0; r < ROWS; ++r) {
        float s = (red[0 * ROWS + r] + red[1 * ROWS + r]) +
                  (red[2 * ROWS + r] + red[3 * ROWS + r]);
        inv[r] = 1.0f / s;
    }

    // ---- phase B: recompute, scale, stream out ----
    #pragma unroll 2
    for (int js = 0; js < N / 256; ++js) {
        int j = js * 256 + t;
        const float4* p = (const float4*)(packed + (size_t)j * PACK);
        float4 v0 = p[0], v1 = p[1], v2 = p[2], v3 = p[3], v4 = p[4];
        float zj[16] = {v0.x, v0.y, v0.z, v0.w, v1.x, v1.y, v1.z, v1.w,
                        v2.x, v2.y, v2.z, v2.w, v3.x, v3.y, v3.z, v3.w};
        float sqj = v4.x;
        #pragma unroll
        for (int r = 0; r < ROWS; ++r) {
            float d0 = 0.0f, d1 = 0.0f;
            #pragma unroll
            for (int k = 0; k < 8; ++k) {
                d0 = fmaf(zi[r][2*k],   zj[2*k],   d0);
                d1 = fmaf(zi[r][2*k+1], zj[2*k+1], d1);
            }
            float dist = fmaxf(fmaf(-2.0f, d0 + d1, sqi[r] + sqj), 0.0f);
            float num = __builtin_amdgcn_rcpf(1.0f + dist);
            __builtin_nontemporal_store(num * inv[r], &out[(size_t)(i0 + r) * N + j]);
        }
    }
}

extern "C" void kernel_launch(void* const* d_in, const int* in_sizes, int n_in,
                              void* d_out, int out_size, void* d_ws, size_t ws_size,
                              hipStream_t stream) {
    const float* x  = (const float*)d_in[0];
    const float* W1 = (const float*)d_in[1];
    const float* b1 = (const float*)d_in[2];
    const float* W2 = (const float*)d_in[3];
    const float* b2 = (const float*)d_in[4];
    const float* W3 = (const float*)d_in[5];
    const float* b3 = (const float*)d_in[6];
    const float* W4 = (const float*)d_in[7];
    const float* b4 = (const float*)d_in[8];
    float* out = (float*)d_out;

    float* packed = (float*)d_ws;   // N*PACK = 163840 floats (640 KiB)

    encoder_kernel<<<128, 64, 0, stream>>>(x, W1, b1, W2, b2, W3, b3, W4, b4, packed);
    prob_kernel<<<N / ROWS, 256, 0, stream>>>(packed, out);
}